// Round 9
// baseline (192.365 us; speedup 1.0000x reference)
//
#include <hip/hip_runtime.h>
#include <stdint.h>

#define NPIX   16384
#define KC     8192
#define DD     64
#define EMS    8193          // embed row stride (K+1)
#define OUT_QUANT 0
#define OUT_DMIN  1048576
#define OUT_IND   (1048576 + 16384)

typedef _Float16 f16;
typedef _Float16 f16x8 __attribute__((ext_vector_type(8)));
typedef float    f32x4 __attribute__((ext_vector_type(4)));
typedef unsigned long long u64;

// async global->LDS, 16B/lane; dest = wave-uniform base (+lane*16 by HW)
__device__ __forceinline__ void gld_lds16(const void* g, void* l) {
    __builtin_amdgcn_global_load_lds(
        (const __attribute__((address_space(1))) uint32_t*)g,
        (__attribute__((address_space(3))) uint32_t*)l, 16, 0, 0);
}

// ---------------------------------------------------------------------------
// Prep X: split fp32 x into f16 hi/lo, store k-slot-blocked A3[16][NPIX][8].
// Slots 0..7 = Xh (d = slot*8..+7), slots 8..15 = Xl.
// ---------------------------------------------------------------------------
__global__ __launch_bounds__(256)
void vq_prep_x(const float* __restrict__ x, f16* __restrict__ A3) {
    int n = blockIdx.x * 256 + threadIdx.x;
#pragma unroll
    for (int s = 0; s < 8; ++s) {
        f16x8 hv, lv;
#pragma unroll
        for (int j = 0; j < 8; ++j) {
            float v = x[(s * 8 + j) * NPIX + n];
            f16 h = (f16)v;
            hv[j] = h;
            lv[j] = (f16)(v - (float)h);
        }
        *(f16x8*)&A3[((u64)(s)     * NPIX + n) * 8] = hv;
        *(f16x8*)&A3[((u64)(s + 8) * NPIX + n) * 8] = lv;
    }
}

// ---------------------------------------------------------------------------
// Prep E: split embed into f16 hi/lo B3[16][KC][8] + masked norms cn.
// ---------------------------------------------------------------------------
__global__ __launch_bounds__(256)
void vq_prep_e(const float* __restrict__ em, const int* __restrict__ cnt,
               f16* __restrict__ B3, float* __restrict__ cn) {
    int k = blockIdx.x * 256 + threadIdx.x;
    float s2 = 0.f;
#pragma unroll
    for (int s = 0; s < 8; ++s) {
        f16x8 hv, lv;
#pragma unroll
        for (int j = 0; j < 8; ++j) {
            float v = em[(s * 8 + j) * EMS + k];
            f16 h = (f16)v;
            hv[j] = h;
            lv[j] = (f16)(v - (float)h);
            s2 = fmaf(v, v, s2);
        }
        *(f16x8*)&B3[((u64)(s)     * KC + k) * 8] = hv;
        *(f16x8*)&B3[((u64)(s + 8) * KC + k) * 8] = lv;
    }
    cn[k] = (cnt[k] < 1) ? 1.0e30f : s2;
}

// ---------------------------------------------------------------------------
// MFMA distance GEMM + fused per-group argmin (atomicMin).
// Split product: x.e = Xh.Eh + Xl.Eh + Xh.El  -> 6 K-steps of 32 (K=192).
// Block: 128 pixels x 512 codes (4 ns-subtiles of 128 codes), 4 waves.
// Per ns: ALL 16 B k-slots staged to LDS once (32 KB, 2 barriers), A
// fragments loaded from global per kt with 1-ahead register prefetch
// (L1/L2-hot, 256B-contiguous per l4 group). LDS reads: 16/wave/ns.
// Epilogue: pack dist(+1024 bias)|col into u64, 16-lane reduce, atomicMin.
// ---------------------------------------------------------------------------
__global__ __launch_bounds__(256, 3)
void vq_mfma(const f16* __restrict__ A3, const f16* __restrict__ B3,
             const float* __restrict__ cn, u64* __restrict__ pk) {
    __shared__ f16 Bs[16384];   // [16 slot][128 code][8]

    const int bid = blockIdx.x;
    const int nb  = bid >> 7;        // 0..15 (512-code groups)
    const int mb  = bid & 127;       // 0..127 (128-pixel tiles)
    const int m0  = mb * 128;
    const int n0  = nb * 512;
    const int t = threadIdx.x, lane = t & 63, w = t >> 6;
    const int wr = w >> 1, wc = w & 1;
    const int l15 = lane & 15, l4 = lane >> 4;

    const int arow = m0 + wr * 64 + l15;        // + m*16
    const u64 pkb  = (u64)(nb * 2 + wc) * NPIX;

    const int sa_t[6] = {0, 4, 8, 12, 0, 4};
    const int sb_t[6] = {0, 4, 0, 4, 8, 12};

    const f32x4 zero4 = {0.f, 0.f, 0.f, 0.f};

#pragma unroll 1
    for (int ns = 0; ns < 4; ++ns) {
        const int nsub = n0 + ns * 128;

        __syncthreads();                  // previous ns done reading Bs
        // ---- stage all 16 B slots for this ns: 8 x 1KB instrs per wave ----
#pragma unroll
        for (int j = 0; j < 8; ++j) {
            int q = w * 8 + j;            // 0..31: slot q>>1, half q&1
            gld_lds16(B3 + ((u64)(q >> 1) * KC + nsub + (q & 1) * 64 + lane) * 8,
                      Bs + q * 512);
        }
        // ---- kt=0 A fragments from global (overlaps the staging drain) ----
        f16x8 afc[4], afn[4];
#pragma unroll
        for (int m = 0; m < 4; ++m)
            afc[m] = *(const f16x8*)&A3[((u64)l4 * NPIX + arow + m * 16) * 8];
        __syncthreads();                  // vmcnt drain + barrier

        f32x4 acc[4][4];
#pragma unroll
        for (int m = 0; m < 4; ++m)
#pragma unroll
            for (int n = 0; n < 4; ++n) acc[m][n] = zero4;

#pragma unroll
        for (int kt = 0; kt < 6; ++kt) {
            if (kt < 5) {                 // prefetch next kt's A frags
                const int sa = sa_t[kt + 1];
#pragma unroll
                for (int m = 0; m < 4; ++m)
                    afn[m] = *(const f16x8*)&A3[((u64)(sa + l4) * NPIX + arow + m * 16) * 8];
            }
            const int sb = sb_t[kt];
            f16x8 bf[4];
#pragma unroll
            for (int n = 0; n < 4; ++n)
                bf[n] = *(const f16x8*)&Bs[((sb + l4) * 128 + wc * 64 + n * 16 + l15) * 8];
#pragma unroll
            for (int m = 0; m < 4; ++m)
#pragma unroll
                for (int n = 0; n < 4; ++n)
                    acc[m][n] = __builtin_amdgcn_mfma_f32_16x16x32_f16(
                        afc[m], bf[n], acc[m][n], 0, 0, 0);
            if (kt < 5) {
#pragma unroll
                for (int m = 0; m < 4; ++m) afc[m] = afn[m];
            }
        }

        // ---- epilogue: dist = cn - 2*dot (+1024 bias), pack, reduce ----
        const int cb = nsub + wc * 64 + l15;
        float cnv[4];
        int   col[4];
#pragma unroll
        for (int n = 0; n < 4; ++n) { col[n] = cb + n * 16; cnv[n] = cn[col[n]]; }
#pragma unroll
        for (int m = 0; m < 4; ++m)
#pragma unroll
            for (int r = 0; r < 4; ++r) {
                u64 best = ~0ull;
#pragma unroll
                for (int n = 0; n < 4; ++n) {
                    float dist = fmaf(-2.f, acc[m][n][r], cnv[n]) + 1024.f;
                    u64 p = ((u64)__float_as_uint(dist) << 32) | (u64)col[n];
                    best = (p < best) ? p : best;
                }
#pragma unroll
                for (int off = 1; off < 16; off <<= 1) {
                    u64 o = __shfl_xor(best, off, 64);
                    best = (o < best) ? o : best;
                }
                if (l15 == 0) {
                    int row = m0 + wr * 64 + m * 16 + l4 * 4 + r;
                    atomicMin(&pk[pkb + row], best);
                }
            }
    }
}

// ---------------------------------------------------------------------------
// Finalize: global top-2 candidates from 32 group minima, exact fp32
// recompute of both distances, strict-< / lowest-index pick, write outputs.
// ---------------------------------------------------------------------------
__global__ __launch_bounds__(256)
void vq_finalize(const float* __restrict__ x, const float* __restrict__ em,
                 const float* __restrict__ cn, const u64* __restrict__ pk,
                 float* __restrict__ out) {
    int n = blockIdx.x * 256 + threadIdx.x;
    u64 b1 = ~0ull, b2 = ~0ull;
#pragma unroll 4
    for (int g = 0; g < 32; ++g) {
        u64 v = pk[(u64)g * NPIX + n];
        if (v < b1)      { b2 = b1; b1 = v; }
        else if (v < b2) { b2 = v; }
    }
    int i1 = (int)(b1 & 0xffffffffull);
    int i2 = (int)(b2 & 0xffffffffull);

    float rn = 0.f, dot1 = 0.f, dot2 = 0.f;
#pragma unroll 8
    for (int d = 0; d < DD; ++d) {
        float xv = x[d * NPIX + n];
        rn   = fmaf(xv, xv, rn);
        dot1 = fmaf(xv, em[d * EMS + i1], dot1);
        dot2 = fmaf(xv, em[d * EMS + i2], dot2);
    }
    float D1 = rn + cn[i1] - 2.f * dot1;
    float D2 = rn + cn[i2] - 2.f * dot2;
    int bi; float db;
    if (D2 < D1 || (D2 == D1 && i2 < i1)) { bi = i2; db = D2; }
    else                                  { bi = i1; db = D1; }

    out[OUT_DMIN + n] = db;
    out[OUT_IND  + n] = (float)bi;
#pragma unroll 8
    for (int d = 0; d < DD; ++d)
        out[OUT_QUANT + d * NPIX + n] = em[d * EMS + bi];
}

// ---------------------------------------------------------------------------
extern "C" void kernel_launch(void* const* d_in, const int* in_sizes, int n_in,
                              void* d_out, int out_size, void* d_ws, size_t ws_size,
                              hipStream_t stream) {
    const float* x     = (const float*)d_in[0];   // [1,64,128,128]
    const float* embed = (const float*)d_in[1];   // [64,8193]
    const int*   cnt   = (const int*)d_in[2];     // [8192]
    float* out = (float*)d_out;

    // ws layout: A3 4MB | B3 2MB | pk 4MB | cn 32KB   (10.06 MB total)
    f16*   A3 = (f16*)d_ws;
    f16*   B3 = (f16*)((char*)d_ws + (size_t)4 * 1024 * 1024);
    u64*   pk = (u64*)((char*)d_ws + (size_t)6 * 1024 * 1024);
    float* cn = (float*)((char*)d_ws + (size_t)10 * 1024 * 1024);

    hipMemsetAsync(pk, 0xFF, (size_t)32 * NPIX * sizeof(u64), stream);
    vq_prep_x<<<NPIX / 256, 256, 0, stream>>>(x, A3);
    vq_prep_e<<<KC / 256, 256, 0, stream>>>(embed, cnt, B3, cn);
    vq_mfma<<<128 * 16, 256, 0, stream>>>(A3, B3, cn, pk);
    vq_finalize<<<NPIX / 256, 256, 0, stream>>>(x, embed, cn, pk, out);
}

// Round 10
// 110.565 us; speedup vs baseline: 1.7398x; 1.7398x over previous
//
#include <hip/hip_runtime.h>
#include <stdint.h>

#define NPIX   16384
#define KC     8192
#define DD     64
#define EMS    8193          // embed row stride (K+1)
#define OUT_QUANT 0
#define OUT_DMIN  1048576
#define OUT_IND   (1048576 + 16384)

typedef _Float16 f16;
typedef _Float16 f16x8 __attribute__((ext_vector_type(8)));
typedef float    f32x4 __attribute__((ext_vector_type(4)));
typedef unsigned long long u64;

// async global->LDS, 16B/lane; dest = wave-uniform base (+lane*16 by HW)
__device__ __forceinline__ void gld_lds16(const void* g, void* l) {
    __builtin_amdgcn_global_load_lds(
        (const __attribute__((address_space(1))) uint32_t*)g,
        (__attribute__((address_space(3))) uint32_t*)l, 16, 0, 0);
}

// ---------------------------------------------------------------------------
// Prep X: split fp32 x into f16 hi/lo, store k-slot-blocked A3[16][NPIX][8].
// Slots 0..7 = Xh (d = slot*8..+7), slots 8..15 = Xl.
// ---------------------------------------------------------------------------
__global__ __launch_bounds__(256)
void vq_prep_x(const float* __restrict__ x, f16* __restrict__ A3) {
    int n = blockIdx.x * 256 + threadIdx.x;
#pragma unroll
    for (int s = 0; s < 8; ++s) {
        f16x8 hv, lv;
#pragma unroll
        for (int j = 0; j < 8; ++j) {
            float v = x[(s * 8 + j) * NPIX + n];
            f16 h = (f16)v;
            hv[j] = h;
            lv[j] = (f16)(v - (float)h);
        }
        *(f16x8*)&A3[((u64)(s)     * NPIX + n) * 8] = hv;
        *(f16x8*)&A3[((u64)(s + 8) * NPIX + n) * 8] = lv;
    }
}

// ---------------------------------------------------------------------------
// Prep E: split embed into f16 hi/lo B3[16][KC][8] + masked norms cn.
// ---------------------------------------------------------------------------
__global__ __launch_bounds__(256)
void vq_prep_e(const float* __restrict__ em, const int* __restrict__ cnt,
               f16* __restrict__ B3, float* __restrict__ cn) {
    int k = blockIdx.x * 256 + threadIdx.x;
    float s2 = 0.f;
#pragma unroll
    for (int s = 0; s < 8; ++s) {
        f16x8 hv, lv;
#pragma unroll
        for (int j = 0; j < 8; ++j) {
            float v = em[(s * 8 + j) * EMS + k];
            f16 h = (f16)v;
            hv[j] = h;
            lv[j] = (f16)(v - (float)h);
            s2 = fmaf(v, v, s2);
        }
        *(f16x8*)&B3[((u64)(s)     * KC + k) * 8] = hv;
        *(f16x8*)&B3[((u64)(s + 8) * KC + k) * 8] = lv;
    }
    cn[k] = (cnt[k] < 1) ? 1.0e30f : s2;
}

// ---------------------------------------------------------------------------
// MFMA distance GEMM + fused per-group packed argmin.
// Split product: x.e = Xh.Eh + Xl.Eh + Xh.El  -> 6 K-steps of 32 (K=192).
// Block: 128 pixels x 512 codes (4 ns-subtiles), 4 waves, wave quad 64x64.
// A staged to LDS ONCE per block (16 slots, 32 KB); B staged once per ns
// (32 KB). 7 barriers/block total (was 48 in R8); no per-lane global loads
// in the hot loop (R9's spill trap). rmin in registers, direct pk writes.
// ---------------------------------------------------------------------------
__global__ __launch_bounds__(256, 2)
void vq_mfma(const f16* __restrict__ A3, const f16* __restrict__ B3,
             const float* __restrict__ cn, u64* __restrict__ pk) {
    __shared__ f16 As[16384];   // [16 slot][128 row][8]
    __shared__ f16 Bs[16384];   // [16 slot][128 code][8]

    const int bid = blockIdx.x;
    const int nb  = bid >> 7;        // 0..15 (512-code groups)
    const int mb  = bid & 127;       // 0..127 (128-pixel tiles)
    const int m0  = mb * 128;
    const int n0  = nb * 512;
    const int t = threadIdx.x, lane = t & 63, w = t >> 6;
    const int wr = w >> 1, wc = w & 1;
    const int l15 = lane & 15, l4 = lane >> 4;

    static const int sa_t[6] = {0, 4, 8, 12, 0, 4};
    static const int sb_t[6] = {0, 4, 0, 4, 8, 12};

    u64 rmin[16];
#pragma unroll
    for (int i = 0; i < 16; ++i) rmin[i] = ~0ull;

    const f32x4 zero4 = {0.f, 0.f, 0.f, 0.f};

    // ---- stage A (whole block, once) + B for ns=0 ----
#pragma unroll
    for (int j = 0; j < 8; ++j) {
        int q = w * 8 + j;           // 0..31: slot q>>1, half q&1
        gld_lds16(A3 + ((u64)(q >> 1) * NPIX + m0 + (q & 1) * 64 + lane) * 8,
                  As + q * 512);
        gld_lds16(B3 + ((u64)(q >> 1) * KC + n0 + (q & 1) * 64 + lane) * 8,
                  Bs + q * 512);
    }
    __syncthreads();                 // vmcnt drain + barrier

#pragma unroll 1
    for (int ns = 0; ns < 4; ++ns) {
        const int nsub = n0 + ns * 128;

        f32x4 acc[4][4];
#pragma unroll
        for (int m = 0; m < 4; ++m)
#pragma unroll
            for (int n = 0; n < 4; ++n) acc[m][n] = zero4;

#pragma unroll
        for (int kt = 0; kt < 6; ++kt) {
            const int sa = sa_t[kt], sb = sb_t[kt];
            f16x8 af[4], bf[4];
#pragma unroll
            for (int m = 0; m < 4; ++m)
                af[m] = *(const f16x8*)&As[((sa + l4) * 128 + wr * 64 + m * 16 + l15) * 8];
#pragma unroll
            for (int n = 0; n < 4; ++n)
                bf[n] = *(const f16x8*)&Bs[((sb + l4) * 128 + wc * 64 + n * 16 + l15) * 8];
#pragma unroll
            for (int m = 0; m < 4; ++m)
#pragma unroll
                for (int n = 0; n < 4; ++n)
                    acc[m][n] = __builtin_amdgcn_mfma_f32_16x16x32_f16(
                        af[m], bf[n], acc[m][n], 0, 0, 0);
        }

        // ---- epilogue: dist = cn - 2*dot (+1024 bias), pack, running min ----
        const int cb = nsub + wc * 64 + l15;
        float cnv[4];
        int   col[4];
#pragma unroll
        for (int n = 0; n < 4; ++n) { col[n] = cb + n * 16; cnv[n] = cn[col[n]]; }
#pragma unroll
        for (int m = 0; m < 4; ++m)
#pragma unroll
            for (int r = 0; r < 4; ++r) {
                u64 best = rmin[m * 4 + r];
#pragma unroll
                for (int n = 0; n < 4; ++n) {
                    float dist = fmaf(-2.f, acc[m][n][r], cnv[n]) + 1024.f;
                    u64 p = ((u64)__float_as_uint(dist) << 32) | (u64)col[n];
                    best = (p < best) ? p : best;
                }
                rmin[m * 4 + r] = best;
            }

        // ---- restage B for next ns ----
        if (ns < 3) {
            __syncthreads();         // all waves done reading Bs
#pragma unroll
            for (int j = 0; j < 8; ++j) {
                int q = w * 8 + j;
                gld_lds16(B3 + ((u64)(q >> 1) * KC + nsub + 128 + (q & 1) * 64 + lane) * 8,
                          Bs + q * 512);
            }
            __syncthreads();         // vmcnt drain + barrier
        }
    }

    // ---- 16-lane reduce, one write per (group,row) ----
    const u64 pkb = (u64)(nb * 2 + wc) * NPIX;
#pragma unroll
    for (int m = 0; m < 4; ++m)
#pragma unroll
        for (int r = 0; r < 4; ++r) {
            u64 v = rmin[m * 4 + r];
#pragma unroll
            for (int off = 1; off < 16; off <<= 1) {
                u64 o = __shfl_xor(v, off, 64);
                v = (o < v) ? o : v;
            }
            if (l15 == 0) {
                int row = m0 + wr * 64 + m * 16 + l4 * 4 + r;
                pk[pkb + row] = v;
            }
        }
}

// ---------------------------------------------------------------------------
// Finalize: global top-2 candidates from 32 group minima, exact fp32
// recompute of both distances, strict-< / lowest-index pick, write outputs.
// ---------------------------------------------------------------------------
__global__ __launch_bounds__(256)
void vq_finalize(const float* __restrict__ x, const float* __restrict__ em,
                 const float* __restrict__ cn, const u64* __restrict__ pk,
                 float* __restrict__ out) {
    int n = blockIdx.x * 256 + threadIdx.x;
    u64 b1 = ~0ull, b2 = ~0ull;
#pragma unroll 4
    for (int g = 0; g < 32; ++g) {
        u64 v = pk[(u64)g * NPIX + n];
        if (v < b1)      { b2 = b1; b1 = v; }
        else if (v < b2) { b2 = v; }
    }
    int i1 = (int)(b1 & 0xffffffffull);
    int i2 = (int)(b2 & 0xffffffffull);

    float rn = 0.f, dot1 = 0.f, dot2 = 0.f;
#pragma unroll 8
    for (int d = 0; d < DD; ++d) {
        float xv = x[d * NPIX + n];
        rn   = fmaf(xv, xv, rn);
        dot1 = fmaf(xv, em[d * EMS + i1], dot1);
        dot2 = fmaf(xv, em[d * EMS + i2], dot2);
    }
    float D1 = rn + cn[i1] - 2.f * dot1;
    float D2 = rn + cn[i2] - 2.f * dot2;
    int bi; float db;
    if (D2 < D1 || (D2 == D1 && i2 < i1)) { bi = i2; db = D2; }
    else                                  { bi = i1; db = D1; }

    out[OUT_DMIN + n] = db;
    out[OUT_IND  + n] = (float)bi;
#pragma unroll 8
    for (int d = 0; d < DD; ++d)
        out[OUT_QUANT + d * NPIX + n] = em[d * EMS + bi];
}

// ---------------------------------------------------------------------------
extern "C" void kernel_launch(void* const* d_in, const int* in_sizes, int n_in,
                              void* d_out, int out_size, void* d_ws, size_t ws_size,
                              hipStream_t stream) {
    const float* x     = (const float*)d_in[0];   // [1,64,128,128]
    const float* embed = (const float*)d_in[1];   // [64,8193]
    const int*   cnt   = (const int*)d_in[2];     // [8192]
    float* out = (float*)d_out;

    // ws layout: A3 4MB | B3 2MB | pk 4MB | cn 32KB   (10.06 MB total)
    f16*   A3 = (f16*)d_ws;
    f16*   B3 = (f16*)((char*)d_ws + (size_t)4 * 1024 * 1024);
    u64*   pk = (u64*)((char*)d_ws + (size_t)6 * 1024 * 1024);
    float* cn = (float*)((char*)d_ws + (size_t)10 * 1024 * 1024);

    vq_prep_x<<<NPIX / 256, 256, 0, stream>>>(x, A3);
    vq_prep_e<<<KC / 256, 256, 0, stream>>>(embed, cnt, B3, cn);
    vq_mfma<<<128 * 16, 256, 0, stream>>>(A3, B3, cn, pk);
    vq_finalize<<<NPIX / 256, 256, 0, stream>>>(x, embed, cn, pk, out);
}